// Round 2
// baseline (953.019 us; speedup 1.0000x reference)
//
#include <hip/hip_runtime.h>

typedef unsigned int uint;
typedef unsigned short ushort;

#define HID 128
#define NGRAPH 64

typedef __attribute__((ext_vector_type(8))) short short8;
typedef __attribute__((ext_vector_type(4))) float floatx4;

__device__ __forceinline__ float bflo(uint w){ return __uint_as_float(w<<16); }
__device__ __forceinline__ float bfhi(uint w){ return __uint_as_float(w & 0xffff0000u); }
__device__ __forceinline__ float bf2f(ushort u){ return __uint_as_float(((uint)u)<<16); }
__device__ __forceinline__ ushort f2bf(float f){
  uint u = __float_as_uint(f);
  u = u + 0x7fffu + ((u>>16)&1u);
  return (ushort)(u>>16);
}
__device__ __forceinline__ uint pack2(float a, float b){
  return (uint)f2bf(a) | ((uint)f2bf(b)<<16);
}
__device__ __forceinline__ float nanz(float v){ return (v==v) ? v : 0.f; }

// edge-index fetch, int32 or int64 (flag) --------------------------------
__device__ __forceinline__ int esrc(const int* ei, int e, int E, int is64){
  return is64 ? ei[2*(size_t)e] : ei[e];
}
__device__ __forceinline__ int edst(const int* ei, int e, int E, int is64){
  return is64 ? ei[2*((size_t)E + e)] : ei[E + e];
}
__device__ __forceinline__ int bat(const int* b, int i, int is64){
  return is64 ? b[2*(size_t)i] : b[i];
}

// ---------------- dtype detector ----------------
// flags[0]=1 if float data looks like packed bf16 (unsupported -> sentinel)
// flags[1]=1 if ints are int64
__global__ void k_detect(const uint* __restrict__ xw32, const int* __restrict__ ei,
                         int* __restrict__ flags){
  __shared__ int h1, h2;
  if (threadIdx.x == 0){ h1 = 0; h2 = 0; }
  __syncthreads();
  int t = threadIdx.x; // 256
  int local = 0;
  #pragma unroll
  for (int k = 0; k < 4; k++){
    uint w = xw32[t*4 + k];
    uint e = (w >> 7) & 0xFF;      // f32: random mantissa byte; bf16-pair: exponent byte
    if (e >= 0x30 && e <= 0x43) local++;
  }
  atomicAdd(&h1, local);
  if (t < 128){ if (ei[2*t + 1] != 0) atomicAdd(&h2, 1); }
  __syncthreads();
  if (t == 0){
    flags[0] = (h1 > 512) ? 1 : 0;
    flags[1] = (h2 == 0) ? 1 : 0;
  }
}

// writes sentinel 123.0-bf16 pattern if float dtype unsupported
__global__ void k_flagout(const int* __restrict__ flags, ushort* out, int n){
  if (flags[0] == 0) return;
  int i = threadIdx.x;
  if (i < n) out[i] = 0x42F6; // bf16(123.0)
}

__global__ void k_sentinel(ushort* out, int n){  // ws too small: 77.0 pattern
  int i = blockIdx.x*blockDim.x + threadIdx.x;
  if (i < n) out[i] = 0x429A;
}

// ---------------- CSR build ----------------

__global__ void k_hist(const int* __restrict__ ei, int* __restrict__ cnt, int E, int NN,
                       const int* __restrict__ flags){
  int is64 = flags[1];
  int e = blockIdx.x*blockDim.x + threadIdx.x;
  if (e < E){ int d = edst(ei, e, E, is64); if ((uint)d < (uint)NN) atomicAdd(&cnt[d], 1); }
}

__global__ void k_scan1(const int* __restrict__ cnt, int* __restrict__ partials,
                        float* __restrict__ dinv, int NN){
  int t = threadIdx.x;
  int base = blockIdx.x*1024 + t*4;
  int v0=0,v1=0,v2=0,v3=0;
  if (base + 3 < NN){ int4 v = *(const int4*)(cnt + base); v0=v.x; v1=v.y; v2=v.z; v3=v.w; }
  else {
    if (base+0 < NN) v0 = cnt[base+0];
    if (base+1 < NN) v1 = cnt[base+1];
    if (base+2 < NN) v2 = cnt[base+2];
    if (base+3 < NN) v3 = cnt[base+3];
  }
  if (base+0 < NN) dinv[base+0] = rsqrtf((float)(v0+1));
  if (base+1 < NN) dinv[base+1] = rsqrtf((float)(v1+1));
  if (base+2 < NN) dinv[base+2] = rsqrtf((float)(v2+1));
  if (base+3 < NN) dinv[base+3] = rsqrtf((float)(v3+1));
  __shared__ int red[256];
  red[t] = v0+v1+v2+v3;
  __syncthreads();
  for (int off=128; off>0; off>>=1){
    if (t < off) red[t] += red[t+off];
    __syncthreads();
  }
  if (t==0) partials[blockIdx.x] = red[0];
}

__global__ void k_scan2(int* __restrict__ partials, int* __restrict__ offs, int npart, int NN){
  if (threadIdx.x==0 && blockIdx.x==0){
    int run = 0;
    for (int i=0;i<npart;i++){ int tt = partials[i]; partials[i] = run; run += tt; }
    offs[NN] = run;
  }
}

__global__ void k_scan3(const int* __restrict__ cnt, const int* __restrict__ partials,
                        int* __restrict__ offs, int NN){
  int t = threadIdx.x;
  int base = blockIdx.x*1024 + t*4;
  int v0=0,v1=0,v2=0,v3=0;
  if (base + 3 < NN){ int4 v = *(const int4*)(cnt + base); v0=v.x; v1=v.y; v2=v.z; v3=v.w; }
  else {
    if (base+0 < NN) v0 = cnt[base+0];
    if (base+1 < NN) v1 = cnt[base+1];
    if (base+2 < NN) v2 = cnt[base+2];
    if (base+3 < NN) v3 = cnt[base+3];
  }
  int tsum = v0+v1+v2+v3;
  __shared__ int sc[256];
  sc[t] = tsum;
  __syncthreads();
  for (int off=1; off<256; off<<=1){
    int val = (t >= off) ? sc[t-off] : 0;
    __syncthreads();
    sc[t] += val;
    __syncthreads();
  }
  int run = partials[blockIdx.x] + sc[t] - tsum;
  if (base+0 < NN){ offs[base+0] = run; run += v0; }
  if (base+1 < NN){ offs[base+1] = run; run += v1; }
  if (base+2 < NN){ offs[base+2] = run; run += v2; }
  if (base+3 < NN){ offs[base+3] = run; run += v3; }
}

__global__ void k_scatter(const int* __restrict__ ei, const int* __restrict__ offs,
                          int* __restrict__ cursor, int* __restrict__ srclist, int E, int NN,
                          const int* __restrict__ flags){
  int is64 = flags[1];
  int e = blockIdx.x*blockDim.x + threadIdx.x;
  if (e < E){
    int d = edst(ei, e, E, is64), s = esrc(ei, e, E, is64);
    if ((uint)d < (uint)NN && (uint)s < (uint)NN){
      int p = offs[d] + atomicAdd(&cursor[d], 1);
      srclist[p] = s;
    }
  }
}

// ---------------- GEMM: f32 [nrows,128] @ f32 [128,128] -> bf16-packed out ----------------

__global__ void k_gemm(const float* __restrict__ A, const float* __restrict__ W,
                       ushort* __restrict__ O, int nrows, int donan,
                       const int* __restrict__ flags){
  if (flags[0]) return;
  int wave = threadIdx.x >> 6;
  int lane = threadIdx.x & 63;
  int rowbase = blockIdx.x*64 + wave*16;
  if (rowbase >= nrows) return;
  int coltile = blockIdx.y * 16;
  int m = lane & 15;
  int q = lane >> 4;
  const float* arow = A + (size_t)(rowbase + m)*HID;
  floatx4 acc = {0.f,0.f,0.f,0.f};
  #pragma unroll
  for (int ks=0; ks<4; ks++){
    int kb = ks*32 + q*8;
    float4 f0 = *(const float4*)(arow + kb);
    float4 f1 = *(const float4*)(arow + kb + 4);
    if (donan){
      f0.x=nanz(f0.x); f0.y=nanz(f0.y); f0.z=nanz(f0.z); f0.w=nanz(f0.w);
      f1.x=nanz(f1.x); f1.y=nanz(f1.y); f1.z=nanz(f1.z); f1.w=nanz(f1.w);
    }
    short8 af;
    af[0]=(short)f2bf(f0.x); af[1]=(short)f2bf(f0.y); af[2]=(short)f2bf(f0.z); af[3]=(short)f2bf(f0.w);
    af[4]=(short)f2bf(f1.x); af[5]=(short)f2bf(f1.y); af[6]=(short)f2bf(f1.z); af[7]=(short)f2bf(f1.w);
    short8 bfr;
    #pragma unroll
    for (int j=0;j<8;j++) bfr[j] = (short)f2bf(W[(size_t)(kb+j)*HID + coltile + m]);
    acc = __builtin_amdgcn_mfma_f32_16x16x32_bf16(af, bfr, acc, 0, 0, 0);
  }
  #pragma unroll
  for (int i=0;i<4;i++){
    int row = q*4 + i;
    O[(size_t)(rowbase+row)*HID + coltile + m] = f2bf(acc[i]);
  }
}

// ---------------- edge aggregation: one wave per node, fused BN stats ----------------

__global__ void k_agg(const uint* __restrict__ xw, const int* __restrict__ offs,
                      const int* __restrict__ srclist, const float* __restrict__ dinv,
                      uint* __restrict__ agg, float* __restrict__ stats, int NN,
                      const int* __restrict__ flags){
  if (flags[0]) return;
  __shared__ float lstat[256];
  lstat[threadIdx.x] = 0.f;
  __syncthreads();
  int wib = threadIdx.x >> 6;
  int lane = threadIdx.x & 63;
  int wid = blockIdx.x*4 + wib;
  int nw = gridDim.x*4;
  float s0=0.f, s1=0.f, q0=0.f, q1=0.f;
  for (int n = wid; n < NN; n += nw){
    int lo = offs[n], hi = offs[n+1];
    float dvn = dinv[n];
    float a0 = 0.f, a1 = 0.f;
    for (int base = lo; base < hi; base += 64){
      int c = hi - base; if (c > 64) c = 64;
      int sidx = 0; float dvs = 0.f;
      if (lane < c){ sidx = srclist[base + lane]; dvs = dinv[sidx]; }
      #pragma unroll 4
      for (int j = 0; j < c; j++){
        int sj = __shfl(sidx, j, 64);
        float cj = __shfl(dvs, j, 64) * dvn;
        uint w = xw[(size_t)sj*64 + lane];
        a0 += cj * bflo(w);
        a1 += cj * bfhi(w);
      }
    }
    uint w = xw[(size_t)n*64 + lane];     // self loop
    float cs = dvn*dvn;
    a0 += cs * bflo(w);
    a1 += cs * bfhi(w);
    agg[(size_t)n*64 + lane] = pack2(a0, a1);
    s0 += a0; s1 += a1; q0 += a0*a0; q1 += a1*a1;
  }
  int ch = lane*2;
  atomicAdd(&lstat[ch],       s0);
  atomicAdd(&lstat[ch+1],     s1);
  atomicAdd(&lstat[128+ch],   q0);
  atomicAdd(&lstat[128+ch+1], q1);
  __syncthreads();
  atomicAdd(&stats[threadIdx.x], lstat[threadIdx.x]);
}

// ---------------- BN finalize (GCN bias cancels through BN) ----------------

__global__ void k_bnfin(float* __restrict__ stats, const float* __restrict__ gam,
                        const float* __restrict__ bet, float* __restrict__ coef, int NN,
                        const int* __restrict__ flags){
  if (flags[0]) return;
  int t = threadIdx.x; // 128
  float s = stats[t], sq = stats[128+t];
  float inv = 1.f/(float)NN;
  float mean = s*inv;
  float var = fmaxf(sq*inv - mean*mean, 0.f);
  float a = gam[t] * rsqrtf(var + 1e-5f);
  coef[t] = a;
  coef[128+t] = bet[t] - mean*a;
  stats[t] = 0.f; stats[128+t] = 0.f;   // ready for layer 2
}

__global__ void k_bnapply(const uint* __restrict__ agg, const float* __restrict__ coef,
                          uint* __restrict__ h, int nwords, const int* __restrict__ flags){
  if (flags[0]) return;
  int i = blockIdx.x*blockDim.x + threadIdx.x;
  if (i >= nwords) return;
  int ch = (i & 63)*2;
  uint w = agg[i];
  float v0 = fmaxf(coef[ch]  *bflo(w) + coef[128+ch],   0.f);
  float v1 = fmaxf(coef[ch+1]*bfhi(w) + coef[128+ch+1], 0.f);
  h[i] = pack2(v0, v1);
}

// ---------------- pool (batch sorted -> contiguous ranges) ----------------

__global__ void k_pool(const ushort* __restrict__ h, const int* __restrict__ batch,
                       float* __restrict__ pooled, int NN, const int* __restrict__ flags){
  if (flags[0]) return;
  int is64 = flags[1];
  __shared__ int bounds[2];
  int g = blockIdx.x;
  if (threadIdx.x == 0){
    int lo=0, hi=NN;
    while (lo<hi){ int mid=(lo+hi)>>1; if (bat(batch,mid,is64) < g) lo=mid+1; else hi=mid; }
    bounds[0] = lo;
    int lo2=lo, hi2=NN;
    while (lo2<hi2){ int mid=(lo2+hi2)>>1; if (bat(batch,mid,is64) < g+1) lo2=mid+1; else hi2=mid; }
    bounds[1] = lo2;
  }
  __syncthreads();
  int lo = bounds[0], hi = bounds[1];
  int tid = threadIdx.x;              // 512: 4 rowgroups x 128 ch
  int ch = tid & 127, rg = tid >> 7;
  float acc = 0.f;
  for (int r = lo + rg; r < hi; r += 4)
    acc += bf2f(h[(size_t)r*HID + ch]);
  __shared__ float red[512];
  red[tid] = acc;
  __syncthreads();
  if (tid < 128){
    float s = red[tid] + red[tid+128] + red[tid+256] + red[tid+384];
    float c = (float)(hi - lo);
    pooled[g*HID + ch] = s / fmaxf(c, 1.f);
  }
}

// ---------------- classifier MLP (tiny), f32 weights, f32 out ----------------

__global__ void k_mlp(const float* __restrict__ pooled, const float* __restrict__ Wc1,
                      const float* __restrict__ bc1, const float* __restrict__ Wc2,
                      const float* __restrict__ bc2, float* __restrict__ out,
                      const int* __restrict__ flags){
  if (flags[0]) return;
  __shared__ float P[NGRAPH*HID];
  __shared__ float Z[NGRAPH*64];
  int tid = threadIdx.x; // 256
  for (int i = tid; i < NGRAPH*HID; i += 256) P[i] = pooled[i];
  __syncthreads();
  for (int idx = tid; idx < NGRAPH*64; idx += 256){
    int g = idx >> 6, j = idx & 63;
    float acc = bc1[j];
    for (int k = 0; k < HID; k++) acc += P[g*HID + k] * Wc1[k*64 + j];
    Z[idx] = fmaxf(acc, 0.f);
  }
  __syncthreads();
  if (tid < NGRAPH*2){
    int g = tid >> 1, o = tid & 1;
    float acc = bc2[o];
    for (int k = 0; k < 64; k++) acc += Z[g*64 + k] * Wc2[k*2 + o];
    out[tid] = nanz(acc);
  }
}

extern "C" void kernel_launch(void* const* d_in, const int* in_sizes, int n_in,
                              void* d_out, int out_size, void* d_ws, size_t ws_size,
                              hipStream_t stream){
  const float* x   = (const float*)d_in[0];
  const int*   ei  = (const int*)d_in[1];
  const int* batch = (const int*)d_in[2];
  const float* W1  = (const float*)d_in[3];
  // d_in[4] = b1: cancels through BN
  const float* g1  = (const float*)d_in[5];
  const float* be1 = (const float*)d_in[6];
  const float* W2  = (const float*)d_in[7];
  // d_in[8] = b2: cancels through BN
  const float* g2  = (const float*)d_in[9];
  const float* be2 = (const float*)d_in[10];
  const float* Wc1 = (const float*)d_in[11];
  const float* bc1 = (const float*)d_in[12];
  const float* Wc2 = (const float*)d_in[13];
  const float* bc2 = (const float*)d_in[14];

  const int NN = in_sizes[2];        // 100000 nodes
  const int E  = in_sizes[1] / 2;    // 1.6M edges

  char* p = (char*)d_ws;
  auto carve = [&](size_t bytes)->char*{
    char* r = p; p += (bytes + 255) & ~(size_t)255; return r;
  };
  int NPART = (NN + 1023)/1024;
  int*   flags    = (int*)  carve(64*4);
  int*   cnt      = (int*)  carve((size_t)NN*4);
  int*   cursor   = (int*)  carve((size_t)NN*4);
  int*   offs     = (int*)  carve(((size_t)NN+1)*4);
  int*   partials = (int*)  carve((size_t)NPART*4);
  int*   srclist  = (int*)  carve((size_t)E*4);
  float* dinv     = (float*)carve((size_t)NN*4);
  float* stats    = (float*)carve(256*4);
  float* coef     = (float*)carve(256*4);
  float* pooled   = (float*)carve((size_t)NGRAPH*HID*4);
  ushort* xw      = (ushort*)carve((size_t)NN*HID*2);
  ushort* agg     = (ushort*)carve((size_t)NN*HID*2);
  ushort* h       = (ushort*)carve((size_t)NN*HID*2);
  if ((size_t)(p - (char*)d_ws) > ws_size){
    k_sentinel<<<(out_size+255)/256, 256, 0, stream>>>((ushort*)d_out, out_size);
    return;
  }

  hipMemsetAsync(cnt,    0, (size_t)NN*4, stream);
  hipMemsetAsync(cursor, 0, (size_t)NN*4, stream);
  hipMemsetAsync(stats,  0, 256*4, stream);

  k_detect <<<1, 256, 0, stream>>>((const uint*)x, ei, flags);
  k_flagout<<<1, 256, 0, stream>>>(flags, (ushort*)d_out, out_size);

  int eb = (E + 255)/256;
  k_hist   <<<eb, 256, 0, stream>>>(ei, cnt, E, NN, flags);
  k_scan1  <<<NPART, 256, 0, stream>>>(cnt, partials, dinv, NN);
  k_scan2  <<<1, 64, 0, stream>>>(partials, offs, NPART, NN);
  k_scan3  <<<NPART, 256, 0, stream>>>(cnt, partials, offs, NN);
  k_scatter<<<eb, 256, 0, stream>>>(ei, offs, cursor, srclist, E, NN, flags);

  dim3 ggrid((NN + 63)/64, HID/16);
  int nwords = NN*64;
  // layer 1
  k_gemm   <<<ggrid, 256, 0, stream>>>(x, W1, xw, NN, 1, flags);
  k_agg    <<<1024, 256, 0, stream>>>((const uint*)xw, offs, srclist, dinv, (uint*)agg, stats, NN, flags);
  k_bnfin  <<<1, 128, 0, stream>>>(stats, g1, be1, coef, NN, flags);
  k_bnapply<<<(nwords+255)/256, 256, 0, stream>>>((const uint*)agg, coef, (uint*)h, nwords, flags);
  // layer 2 (h is clean, no NaN scrub needed)
  // reuse xw buffer for h@W2
  {
    // convert path: k_gemm reads f32; h is bf16-packed. Use a dedicated bf16-A GEMM below.
  }
  // bf16-A GEMM for layer 2 handled by same kernel? h is bf16-packed; use separate kernel:
  extern __global__ void k_gemm_bf(const ushort*, const float*, ushort*, int, const int*);
  k_gemm_bf<<<ggrid, 256, 0, stream>>>(h, W2, xw, NN, flags);
  k_agg    <<<1024, 256, 0, stream>>>((const uint*)xw, offs, srclist, dinv, (uint*)agg, stats, NN, flags);
  k_bnfin  <<<1, 128, 0, stream>>>(stats, g2, be2, coef, NN, flags);
  k_bnapply<<<(nwords+255)/256, 256, 0, stream>>>((const uint*)agg, coef, (uint*)h, nwords, flags);
  // pool + classifier
  k_pool   <<<NGRAPH, 512, 0, stream>>>(h, batch, pooled, NN, flags);
  k_mlp    <<<1, 256, 0, stream>>>(pooled, Wc1, bc1, Wc2, bc2, (float*)d_out, flags);
}

// layer-2 GEMM: bf16-packed A (internal h) x f32 W -> bf16-packed out
__global__ void k_gemm_bf(const ushort* __restrict__ A, const float* __restrict__ W,
                          ushort* __restrict__ O, int nrows, const int* __restrict__ flags){
  if (flags[0]) return;
  int wave = threadIdx.x >> 6;
  int lane = threadIdx.x & 63;
  int rowbase = blockIdx.x*64 + wave*16;
  if (rowbase >= nrows) return;
  int coltile = blockIdx.y * 16;
  int m = lane & 15;
  int q = lane >> 4;
  const ushort* arow = A + (size_t)(rowbase + m)*HID;
  floatx4 acc = {0.f,0.f,0.f,0.f};
  #pragma unroll
  for (int ks=0; ks<4; ks++){
    int kb = ks*32 + q*8;
    short8 af = *(const short8*)(arow + kb);
    short8 bfr;
    #pragma unroll
    for (int j=0;j<8;j++) bfr[j] = (short)f2bf(W[(size_t)(kb+j)*HID + coltile + m]);
    acc = __builtin_amdgcn_mfma_f32_16x16x32_bf16(af, bfr, acc, 0, 0, 0);
  }
  #pragma unroll
  for (int i=0;i<4;i++){
    int row = q*4 + i;
    O[(size_t)(rowbase+row)*HID + coltile + m] = f2bf(acc[i]);
  }
}

// Round 3
// 684.702 us; speedup vs baseline: 1.3919x; 1.3919x over previous
//
#include <hip/hip_runtime.h>

typedef unsigned int uint;
typedef unsigned short ushort;

#define HID 128
#define NGRAPH 64

typedef __attribute__((ext_vector_type(8))) short short8;
typedef __attribute__((ext_vector_type(4))) float floatx4;

__device__ __forceinline__ float bflo(uint w){ return __uint_as_float(w<<16); }
__device__ __forceinline__ float bfhi(uint w){ return __uint_as_float(w & 0xffff0000u); }
__device__ __forceinline__ float bf2f(ushort u){ return __uint_as_float(((uint)u)<<16); }
__device__ __forceinline__ ushort f2bf(float f){
  uint u = __float_as_uint(f);
  u = u + 0x7fffu + ((u>>16)&1u);
  return (ushort)(u>>16);
}
__device__ __forceinline__ uint pack2(float a, float b){
  return (uint)f2bf(a) | ((uint)f2bf(b)<<16);
}
__device__ __forceinline__ float nanz(float v){ return (v==v) ? v : 0.f; }

__device__ __forceinline__ int esrc(const int* ei, int e, int E, int is64){
  return is64 ? ei[2*(size_t)e] : ei[e];
}
__device__ __forceinline__ int edst(const int* ei, int e, int E, int is64){
  return is64 ? ei[2*((size_t)E + e)] : ei[E + e];
}
__device__ __forceinline__ int bat(const int* b, int i, int is64){
  return is64 ? b[2*(size_t)i] : b[i];
}

// ---------------- int-width detector (int64 vs int32 edge_index) ----------------
__global__ void k_detect(const int* __restrict__ ei, int* __restrict__ flags){
  __shared__ int h2;
  if (threadIdx.x == 0) h2 = 0;
  __syncthreads();
  int t = threadIdx.x; // 256
  if (t < 128){ if (ei[2*t + 1] != 0) atomicAdd(&h2, 1); }
  __syncthreads();
  if (t == 0) flags[1] = (h2 == 0) ? 1 : 0;
}

__global__ void k_sentinel(ushort* out, int n){  // ws too small: 77.0-ish pattern
  int i = blockIdx.x*blockDim.x + threadIdx.x;
  if (i < n) out[i] = 0x429A;
}

// ---------------- W -> bf16 MFMA-B-fragment layout ----------------
// Wt[((ks*8+ct)*64 + lane)*8 + j] = bf16( W[(ks*32 + (lane>>4)*8 + j)*128 + ct*16 + (lane&15)] )
__global__ void k_wprep(const float* __restrict__ W1, const float* __restrict__ W2,
                        ushort* __restrict__ wt1, ushort* __restrict__ wt2){
  const float* W  = (blockIdx.x == 0) ? W1  : W2;
  ushort*      Wt = (blockIdx.x == 0) ? wt1 : wt2;
  for (int o = threadIdx.x; o < 16384; o += 256){
    int j    = o & 7;
    int lane = (o >> 3) & 63;
    int ct   = (o >> 9) & 7;
    int ks   = o >> 12;
    int k = ks*32 + (lane >> 4)*8 + j;
    int n = ct*16 + (lane & 15);
    Wt[o] = f2bf(W[(size_t)k*HID + n]);
  }
}

// ---------------- CSR build ----------------

__global__ void k_hist(const int* __restrict__ ei, int* __restrict__ cnt, int E, int NN,
                       const int* __restrict__ flags){
  int is64 = flags[1];
  int e = blockIdx.x*blockDim.x + threadIdx.x;
  if (e < E){ int d = edst(ei, e, E, is64); if ((uint)d < (uint)NN) atomicAdd(&cnt[d], 1); }
}

__global__ void k_scan1(const int* __restrict__ cnt, int* __restrict__ partials,
                        float* __restrict__ dinv, int NN){
  int t = threadIdx.x;
  int base = blockIdx.x*1024 + t*4;
  int v0=0,v1=0,v2=0,v3=0;
  if (base + 3 < NN){ int4 v = *(const int4*)(cnt + base); v0=v.x; v1=v.y; v2=v.z; v3=v.w; }
  else {
    if (base+0 < NN) v0 = cnt[base+0];
    if (base+1 < NN) v1 = cnt[base+1];
    if (base+2 < NN) v2 = cnt[base+2];
    if (base+3 < NN) v3 = cnt[base+3];
  }
  if (base+0 < NN) dinv[base+0] = rsqrtf((float)(v0+1));
  if (base+1 < NN) dinv[base+1] = rsqrtf((float)(v1+1));
  if (base+2 < NN) dinv[base+2] = rsqrtf((float)(v2+1));
  if (base+3 < NN) dinv[base+3] = rsqrtf((float)(v3+1));
  __shared__ int red[256];
  red[t] = v0+v1+v2+v3;
  __syncthreads();
  for (int off=128; off>0; off>>=1){
    if (t < off) red[t] += red[t+off];
    __syncthreads();
  }
  if (t==0) partials[blockIdx.x] = red[0];
}

__global__ void k_scan2(int* __restrict__ partials, int* __restrict__ offs, int npart, int NN){
  if (threadIdx.x==0 && blockIdx.x==0){
    int run = 0;
    for (int i=0;i<npart;i++){ int tt = partials[i]; partials[i] = run; run += tt; }
    offs[NN] = run;
  }
}

__global__ void k_scan3(const int* __restrict__ cnt, const int* __restrict__ partials,
                        int* __restrict__ offs, int NN){
  int t = threadIdx.x;
  int base = blockIdx.x*1024 + t*4;
  int v0=0,v1=0,v2=0,v3=0;
  if (base + 3 < NN){ int4 v = *(const int4*)(cnt + base); v0=v.x; v1=v.y; v2=v.z; v3=v.w; }
  else {
    if (base+0 < NN) v0 = cnt[base+0];
    if (base+1 < NN) v1 = cnt[base+1];
    if (base+2 < NN) v2 = cnt[base+2];
    if (base+3 < NN) v3 = cnt[base+3];
  }
  int tsum = v0+v1+v2+v3;
  __shared__ int sc[256];
  sc[t] = tsum;
  __syncthreads();
  for (int off=1; off<256; off<<=1){
    int val = (t >= off) ? sc[t-off] : 0;
    __syncthreads();
    sc[t] += val;
    __syncthreads();
  }
  int run = partials[blockIdx.x] + sc[t] - tsum;
  if (base+0 < NN){ offs[base+0] = run; run += v0; }
  if (base+1 < NN){ offs[base+1] = run; run += v1; }
  if (base+2 < NN){ offs[base+2] = run; run += v2; }
  if (base+3 < NN){ offs[base+3] = run; run += v3; }
}

__global__ void k_scatter(const int* __restrict__ ei, const int* __restrict__ offs,
                          int* __restrict__ cursor, int* __restrict__ srclist, int E, int NN,
                          const int* __restrict__ flags){
  int is64 = flags[1];
  int e = blockIdx.x*blockDim.x + threadIdx.x;
  if (e < E){
    int d = edst(ei, e, E, is64), s = esrc(ei, e, E, is64);
    if ((uint)d < (uint)NN && (uint)s < (uint)NN){
      int p = offs[d] + atomicAdd(&cursor[d], 1);
      srclist[p] = s;
    }
  }
}

// ---------------- GEMM1: f32 x [N,128] @ Wt(bf16,frag) -> xws bf16 (scaled by dinv) ----------------

__global__ __launch_bounds__(256) void k_gemm1(const float* __restrict__ A,
    const ushort* __restrict__ Wt, const float* __restrict__ dinv,
    ushort* __restrict__ O, int NN){
  __shared__ ushort wlds[16384];
  int tid = threadIdx.x;
  {
    const uint4* s = (const uint4*)Wt;
    uint4* d = (uint4*)wlds;
    #pragma unroll
    for (int i = 0; i < 8; i++) d[tid + i*256] = s[tid + i*256];
  }
  __syncthreads();
  int wave = tid >> 6, lane = tid & 63, m = lane & 15, q = lane >> 4;
  int rowbase = blockIdx.x*64 + wave*16;
  int ar = rowbase + m; if (ar >= NN) ar = NN-1;
  const float* arow = A + (size_t)ar*HID;
  short8 af[4];
  #pragma unroll
  for (int ks=0; ks<4; ks++){
    int kb = ks*32 + q*8;
    float4 f0 = *(const float4*)(arow + kb);
    float4 f1 = *(const float4*)(arow + kb + 4);
    short8 t;
    t[0]=(short)f2bf(nanz(f0.x)); t[1]=(short)f2bf(nanz(f0.y));
    t[2]=(short)f2bf(nanz(f0.z)); t[3]=(short)f2bf(nanz(f0.w));
    t[4]=(short)f2bf(nanz(f1.x)); t[5]=(short)f2bf(nanz(f1.y));
    t[6]=(short)f2bf(nanz(f1.z)); t[7]=(short)f2bf(nanz(f1.w));
    af[ks] = t;
  }
  floatx4 acc[8];
  #pragma unroll
  for (int ct=0; ct<8; ct++) acc[ct] = (floatx4){0.f,0.f,0.f,0.f};
  #pragma unroll
  for (int ks=0; ks<4; ks++){
    #pragma unroll
    for (int ct=0; ct<8; ct++){
      short8 bfrag = *(const short8*)&wlds[(((ks*8+ct)*64) + lane)*8];
      acc[ct] = __builtin_amdgcn_mfma_f32_16x16x32_bf16(af[ks], bfrag, acc[ct], 0, 0, 0);
    }
  }
  float dv[4];
  #pragma unroll
  for (int i=0;i<4;i++){ int r = rowbase + q*4 + i; dv[i] = (r < NN) ? dinv[r] : 0.f; }
  #pragma unroll
  for (int ct=0; ct<8; ct++){
    #pragma unroll
    for (int i=0;i<4;i++){
      int r = rowbase + q*4 + i;
      if (r < NN) O[(size_t)r*HID + ct*16 + m] = f2bf(acc[ct][i]*dv[i]);
    }
  }
}

// ---------------- GEMM2: BN+ReLU(agg) @ Wt2 -> xws bf16 (scaled by dinv) ----------------

__global__ __launch_bounds__(256) void k_gemm2(const uint* __restrict__ agg,
    const float* __restrict__ coef, const ushort* __restrict__ Wt,
    const float* __restrict__ dinv, ushort* __restrict__ O, int NN){
  __shared__ ushort wlds[16384];
  __shared__ float cA[128], cB[128];
  int tid = threadIdx.x;
  {
    const uint4* s = (const uint4*)Wt;
    uint4* d = (uint4*)wlds;
    #pragma unroll
    for (int i = 0; i < 8; i++) d[tid + i*256] = s[tid + i*256];
    if (tid < 128){ cA[tid] = coef[tid]; cB[tid] = coef[128+tid]; }
  }
  __syncthreads();
  int wave = tid >> 6, lane = tid & 63, m = lane & 15, q = lane >> 4;
  int rowbase = blockIdx.x*64 + wave*16;
  int ar = rowbase + m; if (ar >= NN) ar = NN-1;
  const uint* arow = agg + (size_t)ar*64;
  short8 af[4];
  #pragma unroll
  for (int ks=0; ks<4; ks++){
    int kb = ks*32 + q*8;
    uint4 u = *(const uint4*)(arow + (kb >> 1));
    short8 t;
    uint uw[4] = {u.x, u.y, u.z, u.w};
    #pragma unroll
    for (int p=0; p<4; p++){
      int k0 = kb + 2*p;
      float v0 = fmaxf(cA[k0]  *bflo(uw[p]) + cB[k0],   0.f);
      float v1 = fmaxf(cA[k0+1]*bfhi(uw[p]) + cB[k0+1], 0.f);
      t[2*p]   = (short)f2bf(v0);
      t[2*p+1] = (short)f2bf(v1);
    }
    af[ks] = t;
  }
  floatx4 acc[8];
  #pragma unroll
  for (int ct=0; ct<8; ct++) acc[ct] = (floatx4){0.f,0.f,0.f,0.f};
  #pragma unroll
  for (int ks=0; ks<4; ks++){
    #pragma unroll
    for (int ct=0; ct<8; ct++){
      short8 bfrag = *(const short8*)&wlds[(((ks*8+ct)*64) + lane)*8];
      acc[ct] = __builtin_amdgcn_mfma_f32_16x16x32_bf16(af[ks], bfrag, acc[ct], 0, 0, 0);
    }
  }
  float dv[4];
  #pragma unroll
  for (int i=0;i<4;i++){ int r = rowbase + q*4 + i; dv[i] = (r < NN) ? dinv[r] : 0.f; }
  #pragma unroll
  for (int ct=0; ct<8; ct++){
    #pragma unroll
    for (int i=0;i<4;i++){
      int r = rowbase + q*4 + i;
      if (r < NN) O[(size_t)r*HID + ct*16 + m] = f2bf(acc[ct][i]*dv[i]);
    }
  }
}

// ---------------- aggregation: agg[n] = dvn*(sum_{s in N(n)} xws[s] + xws[n]), fused BN stats ----------------

__global__ __launch_bounds__(256) void k_agg(const uint* __restrict__ xw,
    const int* __restrict__ offs, const int* __restrict__ srclist,
    const float* __restrict__ dinv, uint* __restrict__ agg,
    float* __restrict__ stats, int NN){
  __shared__ float lstat[256];
  lstat[threadIdx.x] = 0.f;
  __syncthreads();
  int wib = threadIdx.x >> 6;
  int lane = threadIdx.x & 63;
  int wid = blockIdx.x*4 + wib;
  int nw = gridDim.x*4;
  float s0=0.f, s1=0.f, q0=0.f, q1=0.f;
  for (int n = wid; n < NN; n += nw){
    int lo = offs[n], hi = offs[n+1];
    float dvn = dinv[n];
    float a0 = 0.f, a1 = 0.f;
    for (int base = lo; base < hi; base += 64){
      int c = hi - base; if (c > 64) c = 64;
      int sidx = (lane < c) ? srclist[base + lane] : 0;
      int ng = (c + 7) >> 3;
      for (int g = 0; g < ng; g++){
        int jb = g*8;
        uint w[8];
        #pragma unroll
        for (int t = 0; t < 8; t++){
          int sj = __shfl(sidx, jb + t, 64);
          w[t] = xw[(size_t)sj*64 + lane];
        }
        #pragma unroll
        for (int t = 0; t < 8; t++){
          uint wv = (jb + t < c) ? w[t] : 0u;
          a0 += bflo(wv);
          a1 += bfhi(wv);
        }
      }
    }
    uint wsf = xw[(size_t)n*64 + lane];     // self loop
    a0 = (a0 + bflo(wsf)) * dvn;
    a1 = (a1 + bfhi(wsf)) * dvn;
    agg[(size_t)n*64 + lane] = pack2(a0, a1);
    s0 += a0; s1 += a1; q0 += a0*a0; q1 += a1*a1;
  }
  int ch = lane*2;
  atomicAdd(&lstat[ch],       s0);
  atomicAdd(&lstat[ch+1],     s1);
  atomicAdd(&lstat[128+ch],   q0);
  atomicAdd(&lstat[128+ch+1], q1);
  __syncthreads();
  atomicAdd(&stats[threadIdx.x], lstat[threadIdx.x]);
}

// ---------------- BN finalize (GCN bias cancels through BN) ----------------

__global__ void k_bnfin(float* __restrict__ stats, const float* __restrict__ gam,
                        const float* __restrict__ bet, float* __restrict__ coef, int NN){
  int t = threadIdx.x; // 128
  float s = stats[t], sq = stats[128+t];
  float inv = 1.f/(float)NN;
  float mean = s*inv;
  float var = fmaxf(sq*inv - mean*mean, 0.f);
  float a = gam[t] * rsqrtf(var + 1e-5f);
  coef[t] = a;
  coef[128+t] = bet[t] - mean*a;
  stats[t] = 0.f; stats[128+t] = 0.f;   // ready for layer 2
}

// ---------------- pool with fused BN+ReLU (batch sorted -> contiguous ranges) ----------------

__global__ void k_pool(const ushort* __restrict__ agg, const int* __restrict__ batch,
                       const float* __restrict__ coef, float* __restrict__ pooled,
                       int NN, const int* __restrict__ flags){
  int is64 = flags[1];
  __shared__ int bounds[2];
  int g = blockIdx.x;
  if (threadIdx.x == 0){
    int lo=0, hi=NN;
    while (lo<hi){ int mid=(lo+hi)>>1; if (bat(batch,mid,is64) < g) lo=mid+1; else hi=mid; }
    bounds[0] = lo;
    int lo2=lo, hi2=NN;
    while (lo2<hi2){ int mid=(lo2+hi2)>>1; if (bat(batch,mid,is64) < g+1) lo2=mid+1; else hi2=mid; }
    bounds[1] = lo2;
  }
  __syncthreads();
  int lo = bounds[0], hi = bounds[1];
  int tid = threadIdx.x;              // 512: 4 rowgroups x 128 ch
  int ch = tid & 127, rg = tid >> 7;
  float a = coef[ch], b = coef[128+ch];
  float acc = 0.f;
  for (int r = lo + rg; r < hi; r += 4)
    acc += fmaxf(a*bf2f(agg[(size_t)r*HID + ch]) + b, 0.f);
  __shared__ float red[512];
  red[tid] = acc;
  __syncthreads();
  if (tid < 128){
    float s = red[tid] + red[tid+128] + red[tid+256] + red[tid+384];
    float c = (float)(hi - lo);
    pooled[g*HID + ch] = s / fmaxf(c, 1.f);
  }
}

// ---------------- classifier MLP (tiny), f32 ----------------

__global__ void k_mlp(const float* __restrict__ pooled, const float* __restrict__ Wc1,
                      const float* __restrict__ bc1, const float* __restrict__ Wc2,
                      const float* __restrict__ bc2, float* __restrict__ out){
  __shared__ float P[NGRAPH*HID];
  __shared__ float Z[NGRAPH*64];
  int tid = threadIdx.x; // 256
  for (int i = tid; i < NGRAPH*HID; i += 256) P[i] = pooled[i];
  __syncthreads();
  for (int idx = tid; idx < NGRAPH*64; idx += 256){
    int g = idx >> 6, j = idx & 63;
    float acc = bc1[j];
    for (int k = 0; k < HID; k++) acc += P[g*HID + k] * Wc1[k*64 + j];
    Z[idx] = fmaxf(acc, 0.f);
  }
  __syncthreads();
  if (tid < NGRAPH*2){
    int g = tid >> 1, o = tid & 1;
    float acc = bc2[o];
    for (int k = 0; k < 64; k++) acc += Z[g*64 + k] * Wc2[k*2 + o];
    out[tid] = nanz(acc);
  }
}

extern "C" void kernel_launch(void* const* d_in, const int* in_sizes, int n_in,
                              void* d_out, int out_size, void* d_ws, size_t ws_size,
                              hipStream_t stream){
  const float* x   = (const float*)d_in[0];
  const int*   ei  = (const int*)d_in[1];
  const int* batch = (const int*)d_in[2];
  const float* W1  = (const float*)d_in[3];
  // d_in[4] = b1: cancels through BN
  const float* g1  = (const float*)d_in[5];
  const float* be1 = (const float*)d_in[6];
  const float* W2  = (const float*)d_in[7];
  // d_in[8] = b2: cancels through BN
  const float* g2  = (const float*)d_in[9];
  const float* be2 = (const float*)d_in[10];
  const float* Wc1 = (const float*)d_in[11];
  const float* bc1 = (const float*)d_in[12];
  const float* Wc2 = (const float*)d_in[13];
  const float* bc2 = (const float*)d_in[14];

  const int NN = in_sizes[2];        // 100000 nodes
  const int E  = in_sizes[1] / 2;    // 1.6M edges

  char* p = (char*)d_ws;
  auto carve = [&](size_t bytes)->char*{
    char* r = p; p += (bytes + 255) & ~(size_t)255; return r;
  };
  int NPART = (NN + 1023)/1024;
  int*   flags    = (int*)  carve(64*4);
  int*   cnt      = (int*)  carve((size_t)NN*4);
  int*   cursor   = (int*)  carve((size_t)NN*4);
  int*   offs     = (int*)  carve(((size_t)NN+1)*4);
  int*   partials = (int*)  carve((size_t)NPART*4);
  int*   srclist  = (int*)  carve((size_t)E*4);
  float* dinv     = (float*)carve((size_t)NN*4);
  float* stats    = (float*)carve(256*4);
  float* coef     = (float*)carve(256*4);
  float* pooled   = (float*)carve((size_t)NGRAPH*HID*4);
  ushort* wt1     = (ushort*)carve(16384*2);
  ushort* wt2     = (ushort*)carve(16384*2);
  ushort* xw      = (ushort*)carve((size_t)NN*HID*2);
  ushort* agg     = (ushort*)carve((size_t)NN*HID*2);
  if ((size_t)(p - (char*)d_ws) > ws_size){
    k_sentinel<<<(out_size+255)/256, 256, 0, stream>>>((ushort*)d_out, out_size);
    return;
  }

  hipMemsetAsync(cnt,    0, (size_t)NN*4, stream);
  hipMemsetAsync(cursor, 0, (size_t)NN*4, stream);
  hipMemsetAsync(stats,  0, 256*4, stream);

  k_detect <<<1, 256, 0, stream>>>(ei, flags);
  k_wprep  <<<2, 256, 0, stream>>>(W1, W2, wt1, wt2);

  int eb = (E + 255)/256;
  k_hist   <<<eb, 256, 0, stream>>>(ei, cnt, E, NN, flags);
  k_scan1  <<<NPART, 256, 0, stream>>>(cnt, partials, dinv, NN);
  k_scan2  <<<1, 64, 0, stream>>>(partials, offs, NPART, NN);
  k_scan3  <<<NPART, 256, 0, stream>>>(cnt, partials, offs, NN);
  k_scatter<<<eb, 256, 0, stream>>>(ei, offs, cursor, srclist, E, NN, flags);

  int gblocks = (NN + 63)/64;
  // layer 1
  k_gemm1<<<gblocks, 256, 0, stream>>>(x, wt1, dinv, xw, NN);
  k_agg  <<<2048, 256, 0, stream>>>((const uint*)xw, offs, srclist, dinv, (uint*)agg, stats, NN);
  k_bnfin<<<1, 128, 0, stream>>>(stats, g1, be1, coef, NN);
  // layer 2 (BN+ReLU fused into A-load)
  k_gemm2<<<gblocks, 256, 0, stream>>>((const uint*)agg, coef, wt2, dinv, xw, NN);
  k_agg  <<<2048, 256, 0, stream>>>((const uint*)xw, offs, srclist, dinv, (uint*)agg, stats, NN);
  k_bnfin<<<1, 128, 0, stream>>>(stats, g2, be2, coef, NN);
  // pool (BN+ReLU fused) + classifier
  k_pool <<<NGRAPH, 512, 0, stream>>>(agg, batch, coef, pooled, NN, flags);
  k_mlp  <<<1, 256, 0, stream>>>(pooled, Wc1, bc1, Wc2, bc2, (float*)d_out);
}

// Round 4
// 609.788 us; speedup vs baseline: 1.5629x; 1.1229x over previous
//
#include <hip/hip_runtime.h>

typedef unsigned int uint;
typedef unsigned short ushort;

#define HID 128
#define NGRAPH 64

typedef __attribute__((ext_vector_type(8))) short short8;
typedef __attribute__((ext_vector_type(4))) float floatx4;

__device__ __forceinline__ float bflo(uint w){ return __uint_as_float(w<<16); }
__device__ __forceinline__ float bfhi(uint w){ return __uint_as_float(w & 0xffff0000u); }
__device__ __forceinline__ float bf2f(ushort u){ return __uint_as_float(((uint)u)<<16); }
__device__ __forceinline__ ushort f2bf(float f){
  uint u = __float_as_uint(f);
  u = u + 0x7fffu + ((u>>16)&1u);
  return (ushort)(u>>16);
}
__device__ __forceinline__ uint pack2(float a, float b){
  return (uint)f2bf(a) | ((uint)f2bf(b)<<16);
}
__device__ __forceinline__ float nanz(float v){ return (v==v) ? v : 0.f; }

__device__ __forceinline__ int esrc(const int* ei, int e, int E, int is64){
  return is64 ? ei[2*(size_t)e] : ei[e];
}
__device__ __forceinline__ int edst(const int* ei, int e, int E, int is64){
  return is64 ? ei[2*((size_t)E + e)] : ei[E + e];
}
__device__ __forceinline__ int bat(const int* b, int i, int is64){
  return is64 ? b[2*(size_t)i] : b[i];
}

// ---------------- int-width detector (int64 vs int32 edge_index) ----------------
__global__ void k_detect(const int* __restrict__ ei, int* __restrict__ flags){
  __shared__ int h2;
  if (threadIdx.x == 0) h2 = 0;
  __syncthreads();
  int t = threadIdx.x; // 256
  if (t < 128){ if (ei[2*t + 1] != 0) atomicAdd(&h2, 1); }
  __syncthreads();
  if (t == 0) flags[1] = (h2 == 0) ? 1 : 0;
}

__global__ void k_sentinel(ushort* out, int n){  // ws too small marker
  int i = blockIdx.x*blockDim.x + threadIdx.x;
  if (i < n) out[i] = 0x429A;
}

// ---------------- W -> bf16 MFMA-B-fragment layout ----------------
__global__ void k_wprep(const float* __restrict__ W1, const float* __restrict__ W2,
                        ushort* __restrict__ wt1, ushort* __restrict__ wt2){
  const float* W  = (blockIdx.x == 0) ? W1  : W2;
  ushort*      Wt = (blockIdx.x == 0) ? wt1 : wt2;
  for (int o = threadIdx.x; o < 16384; o += 256){
    int j    = o & 7;
    int lane = (o >> 3) & 63;
    int ct   = (o >> 9) & 7;
    int ks   = o >> 12;
    int k = ks*32 + (lane >> 4)*8 + j;
    int n = ct*16 + (lane & 15);
    Wt[o] = f2bf(W[(size_t)k*HID + n]);
  }
}

// ---------------- CSR build ----------------

__global__ void k_hist(const int* __restrict__ ei, int* __restrict__ cnt, int E, int NN,
                       const int* __restrict__ flags){
  int is64 = flags[1];
  int e = blockIdx.x*blockDim.x + threadIdx.x;
  if (e < E){ int d = edst(ei, e, E, is64); if ((uint)d < (uint)NN) atomicAdd(&cnt[d], 1); }
}

__global__ void k_scan1(const int* __restrict__ cnt, int* __restrict__ partials,
                        float* __restrict__ dinv, int NN){
  int t = threadIdx.x;
  int base = blockIdx.x*1024 + t*4;
  int v0=0,v1=0,v2=0,v3=0;
  if (base + 3 < NN){ int4 v = *(const int4*)(cnt + base); v0=v.x; v1=v.y; v2=v.z; v3=v.w; }
  else {
    if (base+0 < NN) v0 = cnt[base+0];
    if (base+1 < NN) v1 = cnt[base+1];
    if (base+2 < NN) v2 = cnt[base+2];
    if (base+3 < NN) v3 = cnt[base+3];
  }
  if (base+0 < NN) dinv[base+0] = rsqrtf((float)(v0+1));
  if (base+1 < NN) dinv[base+1] = rsqrtf((float)(v1+1));
  if (base+2 < NN) dinv[base+2] = rsqrtf((float)(v2+1));
  if (base+3 < NN) dinv[base+3] = rsqrtf((float)(v3+1));
  __shared__ int red[256];
  red[t] = v0+v1+v2+v3;
  __syncthreads();
  for (int off=128; off>0; off>>=1){
    if (t < off) red[t] += red[t+off];
    __syncthreads();
  }
  if (t==0) partials[blockIdx.x] = red[0];
}

__global__ void k_scan2(int* __restrict__ partials, int* __restrict__ offs, int npart, int NN){
  if (threadIdx.x==0 && blockIdx.x==0){
    int run = 0;
    for (int i=0;i<npart;i++){ int tt = partials[i]; partials[i] = run; run += tt; }
    offs[NN] = run;
  }
}

__global__ void k_scan3(const int* __restrict__ cnt, const int* __restrict__ partials,
                        int* __restrict__ offs, int NN){
  int t = threadIdx.x;
  int base = blockIdx.x*1024 + t*4;
  int v0=0,v1=0,v2=0,v3=0;
  if (base + 3 < NN){ int4 v = *(const int4*)(cnt + base); v0=v.x; v1=v.y; v2=v.z; v3=v.w; }
  else {
    if (base+0 < NN) v0 = cnt[base+0];
    if (base+1 < NN) v1 = cnt[base+1];
    if (base+2 < NN) v2 = cnt[base+2];
    if (base+3 < NN) v3 = cnt[base+3];
  }
  int tsum = v0+v1+v2+v3;
  __shared__ int sc[256];
  sc[t] = tsum;
  __syncthreads();
  for (int off=1; off<256; off<<=1){
    int val = (t >= off) ? sc[t-off] : 0;
    __syncthreads();
    sc[t] += val;
    __syncthreads();
  }
  int run = partials[blockIdx.x] + sc[t] - tsum;
  if (base+0 < NN){ offs[base+0] = run; run += v0; }
  if (base+1 < NN){ offs[base+1] = run; run += v1; }
  if (base+2 < NN){ offs[base+2] = run; run += v2; }
  if (base+3 < NN){ offs[base+3] = run; run += v3; }
}

__global__ void k_scatter(const int* __restrict__ ei, const int* __restrict__ offs,
                          int* __restrict__ cursor, int* __restrict__ srclist, int E, int NN,
                          const int* __restrict__ flags){
  int is64 = flags[1];
  int e = blockIdx.x*blockDim.x + threadIdx.x;
  if (e < E){
    int d = edst(ei, e, E, is64), s = esrc(ei, e, E, is64);
    if ((uint)d < (uint)NN && (uint)s < (uint)NN){
      int p = offs[d] + atomicAdd(&cursor[d], 1);
      srclist[p] = s;
    }
  }
}

// ---------------- GEMM1: f32 x [N,128] @ Wt(bf16,frag) -> xws bf16 (scaled by dinv) ----------------

__global__ __launch_bounds__(256) void k_gemm1(const float* __restrict__ A,
    const ushort* __restrict__ Wt, const float* __restrict__ dinv,
    ushort* __restrict__ O, int NN){
  __shared__ ushort wlds[16384];
  int tid = threadIdx.x;
  {
    const uint4* s = (const uint4*)Wt;
    uint4* d = (uint4*)wlds;
    #pragma unroll
    for (int i = 0; i < 8; i++) d[tid + i*256] = s[tid + i*256];
  }
  __syncthreads();
  int wave = tid >> 6, lane = tid & 63, m = lane & 15, q = lane >> 4;
  int rowbase = blockIdx.x*64 + wave*16;
  int ar = rowbase + m; if (ar >= NN) ar = NN-1;
  const float* arow = A + (size_t)ar*HID;
  short8 af[4];
  #pragma unroll
  for (int ks=0; ks<4; ks++){
    int kb = ks*32 + q*8;
    float4 f0 = *(const float4*)(arow + kb);
    float4 f1 = *(const float4*)(arow + kb + 4);
    short8 t;
    t[0]=(short)f2bf(nanz(f0.x)); t[1]=(short)f2bf(nanz(f0.y));
    t[2]=(short)f2bf(nanz(f0.z)); t[3]=(short)f2bf(nanz(f0.w));
    t[4]=(short)f2bf(nanz(f1.x)); t[5]=(short)f2bf(nanz(f1.y));
    t[6]=(short)f2bf(nanz(f1.z)); t[7]=(short)f2bf(nanz(f1.w));
    af[ks] = t;
  }
  floatx4 acc[8];
  #pragma unroll
  for (int ct=0; ct<8; ct++) acc[ct] = (floatx4){0.f,0.f,0.f,0.f};
  #pragma unroll
  for (int ks=0; ks<4; ks++){
    #pragma unroll
    for (int ct=0; ct<8; ct++){
      short8 bfrag = *(const short8*)&wlds[(((ks*8+ct)*64) + lane)*8];
      acc[ct] = __builtin_amdgcn_mfma_f32_16x16x32_bf16(af[ks], bfrag, acc[ct], 0, 0, 0);
    }
  }
  float dv[4];
  #pragma unroll
  for (int i=0;i<4;i++){ int r = rowbase + q*4 + i; dv[i] = (r < NN) ? dinv[r] : 0.f; }
  #pragma unroll
  for (int ct=0; ct<8; ct++){
    #pragma unroll
    for (int i=0;i<4;i++){
      int r = rowbase + q*4 + i;
      if (r < NN) O[(size_t)r*HID + ct*16 + m] = f2bf(acc[ct][i]*dv[i]);
    }
  }
}

// ---------------- GEMM2: BN+ReLU(agg) @ Wt2 -> xws bf16 (scaled by dinv) ----------------

__global__ __launch_bounds__(256) void k_gemm2(const uint* __restrict__ agg,
    const float* __restrict__ coef, const ushort* __restrict__ Wt,
    const float* __restrict__ dinv, ushort* __restrict__ O, int NN){
  __shared__ ushort wlds[16384];
  __shared__ float cA[128], cB[128];
  int tid = threadIdx.x;
  {
    const uint4* s = (const uint4*)Wt;
    uint4* d = (uint4*)wlds;
    #pragma unroll
    for (int i = 0; i < 8; i++) d[tid + i*256] = s[tid + i*256];
    if (tid < 128){ cA[tid] = coef[tid]; cB[tid] = coef[128+tid]; }
  }
  __syncthreads();
  int wave = tid >> 6, lane = tid & 63, m = lane & 15, q = lane >> 4;
  int rowbase = blockIdx.x*64 + wave*16;
  int ar = rowbase + m; if (ar >= NN) ar = NN-1;
  const uint* arow = agg + (size_t)ar*64;
  short8 af[4];
  #pragma unroll
  for (int ks=0; ks<4; ks++){
    int kb = ks*32 + q*8;
    uint4 u = *(const uint4*)(arow + (kb >> 1));
    short8 t;
    uint uw[4] = {u.x, u.y, u.z, u.w};
    #pragma unroll
    for (int p=0; p<4; p++){
      int k0 = kb + 2*p;
      float v0 = fmaxf(cA[k0]  *bflo(uw[p]) + cB[k0],   0.f);
      float v1 = fmaxf(cA[k0+1]*bfhi(uw[p]) + cB[k0+1], 0.f);
      t[2*p]   = (short)f2bf(v0);
      t[2*p+1] = (short)f2bf(v1);
    }
    af[ks] = t;
  }
  floatx4 acc[8];
  #pragma unroll
  for (int ct=0; ct<8; ct++) acc[ct] = (floatx4){0.f,0.f,0.f,0.f};
  #pragma unroll
  for (int ks=0; ks<4; ks++){
    #pragma unroll
    for (int ct=0; ct<8; ct++){
      short8 bfrag = *(const short8*)&wlds[(((ks*8+ct)*64) + lane)*8];
      acc[ct] = __builtin_amdgcn_mfma_f32_16x16x32_bf16(af[ks], bfrag, acc[ct], 0, 0, 0);
    }
  }
  float dv[4];
  #pragma unroll
  for (int i=0;i<4;i++){ int r = rowbase + q*4 + i; dv[i] = (r < NN) ? dinv[r] : 0.f; }
  #pragma unroll
  for (int ct=0; ct<8; ct++){
    #pragma unroll
    for (int i=0;i<4;i++){
      int r = rowbase + q*4 + i;
      if (r < NN) O[(size_t)r*HID + ct*16 + m] = f2bf(acc[ct][i]*dv[i]);
    }
  }
}

// ---------------- aggregation: agg[n] = dvn*(sum xws[s] + xws[n]), fused BN stats ----------------

__global__ __launch_bounds__(256) void k_agg(const uint* __restrict__ xw,
    const int* __restrict__ offs, const int* __restrict__ srclist,
    const float* __restrict__ dinv, uint* __restrict__ agg,
    float* __restrict__ stats, int NN){
  __shared__ float lstat[256];
  lstat[threadIdx.x] = 0.f;
  __syncthreads();
  int wib = threadIdx.x >> 6;
  int lane = threadIdx.x & 63;
  int wid = blockIdx.x*4 + wib;
  int nw = gridDim.x*4;
  float s0=0.f, s1=0.f, q0=0.f, q1=0.f;
  for (int n = wid; n < NN; n += nw){
    int lo = offs[n], hi = offs[n+1];
    float dvn = dinv[n];
    float a0 = 0.f, a1 = 0.f;
    for (int base = lo; base < hi; base += 64){
      int c = hi - base; if (c > 64) c = 64;
      int sidx = (lane < c) ? srclist[base + lane] : 0;
      int ng = (c + 7) >> 3;
      for (int g = 0; g < ng; g++){
        int jb = g*8;
        uint w[8];
        #pragma unroll
        for (int t = 0; t < 8; t++){
          int sj = __shfl(sidx, jb + t, 64);
          w[t] = xw[(size_t)sj*64 + lane];
        }
        #pragma unroll
        for (int t = 0; t < 8; t++){
          uint wv = (jb + t < c) ? w[t] : 0u;
          a0 += bflo(wv);
          a1 += bfhi(wv);
        }
      }
    }
    uint wsf = xw[(size_t)n*64 + lane];     // self loop
    a0 = (a0 + bflo(wsf)) * dvn;
    a1 = (a1 + bfhi(wsf)) * dvn;
    agg[(size_t)n*64 + lane] = pack2(a0, a1);
    s0 += a0; s1 += a1; q0 += a0*a0; q1 += a1*a1;
  }
  int ch = lane*2;
  atomicAdd(&lstat[ch],       s0);
  atomicAdd(&lstat[ch+1],     s1);
  atomicAdd(&lstat[128+ch],   q0);
  atomicAdd(&lstat[128+ch+1], q1);
  __syncthreads();
  atomicAdd(&stats[threadIdx.x], lstat[threadIdx.x]);
}

// ---------------- BN finalize (GCN bias cancels through BN) ----------------

__global__ void k_bnfin(float* __restrict__ stats, const float* __restrict__ gam,
                        const float* __restrict__ bet, float* __restrict__ coef, int NN){
  int t = threadIdx.x; // 128
  float s = stats[t], sq = stats[128+t];
  float inv = 1.f/(float)NN;
  float mean = s*inv;
  float var = fmaxf(sq*inv - mean*mean, 0.f);
  float a = gam[t] * rsqrtf(var + 1e-5f);
  coef[t] = a;
  coef[128+t] = bet[t] - mean*a;
  stats[t] = 0.f; stats[128+t] = 0.f;   // ready for layer 2
}

// ---------------- pool: BN+ReLU fused, 16 splits per graph, atomic partial sums ----------------

#define PSPLIT 16

__global__ __launch_bounds__(256) void k_pool(const uint* __restrict__ agg32,
    const int* __restrict__ batch, const float* __restrict__ coef,
    float* __restrict__ pooled, int* __restrict__ counts,
    int NN, const int* __restrict__ flags){
  int is64 = flags[1];
  __shared__ int bounds[2];
  int g  = blockIdx.x;
  int si = blockIdx.y;
  if (threadIdx.x == 0){
    int lo=0, hi=NN;
    while (lo<hi){ int mid=(lo+hi)>>1; if (bat(batch,mid,is64) < g) lo=mid+1; else hi=mid; }
    bounds[0] = lo;
    int lo2=lo, hi2=NN;
    while (lo2<hi2){ int mid=(lo2+hi2)>>1; if (bat(batch,mid,is64) < g+1) lo2=mid+1; else hi2=mid; }
    bounds[1] = lo2;
    if (si == 0) counts[g] = hi2 - lo;
  }
  __syncthreads();
  int lo = bounds[0], hi = bounds[1];
  int cnt = hi - lo;
  int chunk = (cnt + PSPLIT - 1) / PSPLIT;
  int s = lo + si*chunk;
  int e = s + chunk; if (e > hi) e = hi;
  int tid = threadIdx.x;            // 256: 4 rowgroups x 64 lanes (2ch each)
  int lane = tid & 63, rg = tid >> 6;
  int ch = lane*2;
  float a0c = coef[ch],   b0c = coef[128+ch];
  float a1c = coef[ch+1], b1c = coef[128+ch+1];
  float acc0 = 0.f, acc1 = 0.f;
  for (int r = s + rg; r < e; r += 4){
    uint w = agg32[(size_t)r*64 + lane];
    acc0 += fmaxf(a0c*bflo(w) + b0c, 0.f);
    acc1 += fmaxf(a1c*bfhi(w) + b1c, 0.f);
  }
  __shared__ float red[512];
  red[tid] = acc0;
  red[256+tid] = acc1;
  __syncthreads();
  if (tid < 64){
    float s0 = red[tid] + red[tid+64] + red[tid+128] + red[tid+192];
    float s1 = red[256+tid] + red[320+tid] + red[384+tid] + red[448+tid];
    atomicAdd(&pooled[g*HID + ch],     s0);
    atomicAdd(&pooled[g*HID + ch + 1], s1);
  }
}

// ---------------- classifier MLP (tiny), f32; divides pooled sums by counts ----------------

__global__ void k_mlp(const float* __restrict__ pooled, const int* __restrict__ counts,
                      const float* __restrict__ Wc1, const float* __restrict__ bc1,
                      const float* __restrict__ Wc2, const float* __restrict__ bc2,
                      float* __restrict__ out){
  __shared__ float P[NGRAPH*HID];
  __shared__ float Z[NGRAPH*64];
  int tid = threadIdx.x; // 256
  for (int i = tid; i < NGRAPH*HID; i += 256){
    int g = i >> 7;
    float c = (float)counts[g];
    P[i] = pooled[i] / fmaxf(c, 1.f);
  }
  __syncthreads();
  for (int idx = tid; idx < NGRAPH*64; idx += 256){
    int g = idx >> 6, j = idx & 63;
    float acc = bc1[j];
    for (int k = 0; k < HID; k++) acc += P[g*HID + k] * Wc1[k*64 + j];
    Z[idx] = fmaxf(acc, 0.f);
  }
  __syncthreads();
  if (tid < NGRAPH*2){
    int g = tid >> 1, o = tid & 1;
    float acc = bc2[o];
    for (int k = 0; k < 64; k++) acc += Z[g*64 + k] * Wc2[k*2 + o];
    out[tid] = nanz(acc);
  }
}

extern "C" void kernel_launch(void* const* d_in, const int* in_sizes, int n_in,
                              void* d_out, int out_size, void* d_ws, size_t ws_size,
                              hipStream_t stream){
  const float* x   = (const float*)d_in[0];
  const int*   ei  = (const int*)d_in[1];
  const int* batch = (const int*)d_in[2];
  const float* W1  = (const float*)d_in[3];
  // d_in[4] = b1: cancels through BN
  const float* g1  = (const float*)d_in[5];
  const float* be1 = (const float*)d_in[6];
  const float* W2  = (const float*)d_in[7];
  // d_in[8] = b2: cancels through BN
  const float* g2  = (const float*)d_in[9];
  const float* be2 = (const float*)d_in[10];
  const float* Wc1 = (const float*)d_in[11];
  const float* bc1 = (const float*)d_in[12];
  const float* Wc2 = (const float*)d_in[13];
  const float* bc2 = (const float*)d_in[14];

  const int NN = in_sizes[2];        // 100000 nodes
  const int E  = in_sizes[1] / 2;    // 1.6M edges

  char* p = (char*)d_ws;
  auto carve = [&](size_t bytes)->char*{
    char* r = p; p += (bytes + 255) & ~(size_t)255; return r;
  };
  int NPART = (NN + 1023)/1024;
  int*   flags    = (int*)  carve(64*4);
  int*   cnt      = (int*)  carve((size_t)NN*4);
  int*   cursor   = (int*)  carve((size_t)NN*4);
  int*   offs     = (int*)  carve(((size_t)NN+1)*4);
  int*   partials = (int*)  carve((size_t)NPART*4);
  int*   srclist  = (int*)  carve((size_t)E*4);
  float* dinv     = (float*)carve((size_t)NN*4);
  float* stats    = (float*)carve(256*4);
  float* coef     = (float*)carve(256*4);
  float* pooled   = (float*)carve((size_t)NGRAPH*HID*4);
  int*   counts   = (int*)  carve(NGRAPH*4);
  ushort* wt1     = (ushort*)carve(16384*2);
  ushort* wt2     = (ushort*)carve(16384*2);
  ushort* xw      = (ushort*)carve((size_t)NN*HID*2);
  ushort* agg     = (ushort*)carve((size_t)NN*HID*2);
  if ((size_t)(p - (char*)d_ws) > ws_size){
    k_sentinel<<<(out_size+255)/256, 256, 0, stream>>>((ushort*)d_out, out_size);
    return;
  }

  hipMemsetAsync(cnt,    0, (size_t)NN*4, stream);
  hipMemsetAsync(cursor, 0, (size_t)NN*4, stream);
  hipMemsetAsync(stats,  0, 256*4, stream);
  hipMemsetAsync(pooled, 0, (size_t)NGRAPH*HID*4, stream);

  k_detect <<<1, 256, 0, stream>>>(ei, flags);
  k_wprep  <<<2, 256, 0, stream>>>(W1, W2, wt1, wt2);

  int eb = (E + 255)/256;
  k_hist   <<<eb, 256, 0, stream>>>(ei, cnt, E, NN, flags);
  k_scan1  <<<NPART, 256, 0, stream>>>(cnt, partials, dinv, NN);
  k_scan2  <<<1, 64, 0, stream>>>(partials, offs, NPART, NN);
  k_scan3  <<<NPART, 256, 0, stream>>>(cnt, partials, offs, NN);
  k_scatter<<<eb, 256, 0, stream>>>(ei, offs, cursor, srclist, E, NN, flags);

  int gblocks = (NN + 63)/64;
  // layer 1
  k_gemm1<<<gblocks, 256, 0, stream>>>(x, wt1, dinv, xw, NN);
  k_agg  <<<2048, 256, 0, stream>>>((const uint*)xw, offs, srclist, dinv, (uint*)agg, stats, NN);
  k_bnfin<<<1, 128, 0, stream>>>(stats, g1, be1, coef, NN);
  // layer 2 (BN+ReLU fused into A-load)
  k_gemm2<<<gblocks, 256, 0, stream>>>((const uint*)agg, coef, wt2, dinv, xw, NN);
  k_agg  <<<2048, 256, 0, stream>>>((const uint*)xw, offs, srclist, dinv, (uint*)agg, stats, NN);
  k_bnfin<<<1, 128, 0, stream>>>(stats, g2, be2, coef, NN);
  // pool (BN+ReLU fused, split) + classifier
  k_pool <<<dim3(NGRAPH, PSPLIT), 256, 0, stream>>>((const uint*)agg, batch, coef, pooled, counts, NN, flags);
  k_mlp  <<<1, 256, 0, stream>>>(pooled, counts, Wc1, bc1, Wc2, bc2, (float*)d_out);
}